// Round 1
// baseline (545.029 us; speedup 1.0000x reference)
//
#include <hip/hip_runtime.h>

#define NUM_LEARNERS 50000
#define NUM_SCENES   2000   // 62 full K-steps of 32 + one tail step of 16
#define EMBED_DIM    128
#define HID          16

typedef __attribute__((ext_vector_type(8))) short bf16x8;  // 8 bf16 in 4 VGPRs
typedef __attribute__((ext_vector_type(4))) float f32x4;

union FragU { unsigned int u[4]; bf16x8 v; };

// R5: masked-GEMM restructure. One wave = 16 learner rows.
//   s[k][r] = sum_j mask[j][r] * relu(j*W1[k]+b1[k])  via mfma_f32_16x16x32_bf16
//     A-frag (lane 16g+r): H[r][k=8g+j]   -- computed on the fly, bf16
//     B-frag (lane 16g+r): mask[k=8g+j][r]-- from streaming loads, 1.0/0.0 bf16
//   counts via a second MFMA with A = ones (C rows all equal count[r]).
// No LDS, no barriers, no ballot chains. 4-deep register prefetch ring keeps
// ~4 KB/wave of HBM loads in flight.
__global__ __launch_bounds__(64, 4) void fused_gather_mean_kernel(
    const float* __restrict__ M,
    const float* __restrict__ W1, const float* __restrict__ b1,
    const float* __restrict__ W2, const float* __restrict__ b2,
    float* __restrict__ out)
{
    const int lane = threadIdx.x & 63;   // one wave per block
    const int r    = lane & 15;          // A-row = h-dim ; B-col = learner-in-tile
    const int g    = lane >> 4;          // k-chunk (8 k's) within a 32-wide K-step

    const long row0 = (long)blockIdx.x * 16;           // 3125 blocks, exact
    const float* __restrict__ mrow = M + (row0 + r) * NUM_SCENES;

    const float w1r = W1[r];
    const float b1r = b1[r];

    f32x4 acc_s = {0.f, 0.f, 0.f, 0.f};
    f32x4 acc_c = {0.f, 0.f, 0.f, 0.f};

    FragU ones;                                        // bf16 1.0 pairs
    ones.u[0] = 0x3F803F80u; ones.u[1] = 0x3F803F80u;
    ones.u[2] = 0x3F803F80u; ones.u[3] = 0x3F803F80u;

    // 4-deep prefetch ring (slot index is compile-time after unroll-4).
    float4 ld_lo[4], ld_hi[4];

    auto issue = [&](int t, int slot) {
        int kb = t * 32 + 8 * g;
        kb = (kb > 1992) ? 1992 : kb;   // folds away for t<62; tail g>=2 clamped in-bounds
        const float4* p = (const float4*)(mrow + kb);
        ld_lo[slot] = p[0];
        ld_hi[slot] = p[1];
    };

    auto step = [&](int t, int slot, bool tail) {
        float va[8];
        va[0] = ld_lo[slot].x; va[1] = ld_lo[slot].y;
        va[2] = ld_lo[slot].z; va[3] = ld_lo[slot].w;
        va[4] = ld_hi[slot].x; va[5] = ld_hi[slot].y;
        va[6] = ld_hi[slot].z; va[7] = ld_hi[slot].w;

        // mask fragment: nonzero -> bf16 1.0, packed pairs (elem 2m, 2m+1)
        FragU mf;
#pragma unroll
        for (int m = 0; m < 4; ++m) {
            unsigned int l_ = (va[2 * m]     != 0.0f) ? 0x00003F80u : 0u;
            unsigned int h_ = (va[2 * m + 1] != 0.0f) ? 0x3F800000u : 0u;
            mf.u[m] = l_ | h_;
        }
        if (tail) {  // step 62: only g<2 carry valid k (1984..1999)
            unsigned int keep = (g < 2) ? 0xFFFFFFFFu : 0u;
#pragma unroll
            for (int m = 0; m < 4; ++m) mf.u[m] &= keep;
        }

        // h fragment: relu(k*W1[r]+b1[r]) for k = t*32+8g+j, bf16 RNE via cvt_pk
        const float kbase = (float)(t * 32 + 8 * g);
        FragU hf;
#pragma unroll
        for (int m = 0; m < 4; ++m) {
            float h0 = fmaxf(fmaf(kbase + (float)(2 * m),     w1r, b1r), 0.0f);
            float h1 = fmaxf(fmaf(kbase + (float)(2 * m + 1), w1r, b1r), 0.0f);
            unsigned int pk;
            asm("v_cvt_pk_bf16_f32 %0, %1, %2" : "=v"(pk) : "v"(h0), "v"(h1));
            hf.u[m] = pk;
        }

        acc_s = __builtin_amdgcn_mfma_f32_16x16x32_bf16(hf.v,   mf.v, acc_s, 0, 0, 0);
        acc_c = __builtin_amdgcn_mfma_f32_16x16x32_bf16(ones.v, mf.v, acc_c, 0, 0, 0);
    };

    // prologue: fill the ring (steps 0..3)
#pragma unroll
    for (int t = 0; t < 4; ++t) issue(t, t);

    // main loop: steps 0..59; slot = t&3 is static under unroll-4
#pragma unroll 4
    for (int t = 0; t < 60; ++t) {
        step(t, t & 3, false);
        issue(t + 4, t & 3);   // t=59 issues clamped "step 63" (unused, in-bounds)
    }
    step(60, 0, false);
    step(61, 1, false);
    step(62, 2, true);         // tail (K=16), loaded at t=58

    // ---- epilogue: e[r][d] = (sum_k s[k][r]*W2[k][d] + cnt*b2[d]) / max(cnt,1)
    // acc_s[q] at lane (16g+r) = s[4g+q][r]; gather all 16 k per lane via xor-shfl.
    float sg_[4][4];
#pragma unroll
    for (int q = 0; q < 4; ++q) sg_[0][q] = acc_s[q];                 // k = 4*(g^0)+q
#pragma unroll
    for (int q = 0; q < 4; ++q) sg_[1][q] = __shfl_xor(sg_[0][q], 16); // k = 4*(g^1)+q
#pragma unroll
    for (int q = 0; q < 4; ++q) sg_[2][q] = __shfl_xor(sg_[0][q], 32); // k = 4*(g^2)+q
#pragma unroll
    for (int q = 0; q < 4; ++q) sg_[3][q] = __shfl_xor(sg_[1][q], 32); // k = 4*(g^3)+q

    const float cnt = acc_c[0];                 // exact count[r] (all rows equal)
    const float inv = 1.0f / fmaxf(cnt, 1.0f);

    // lane (16g+r) produces out[row0+r][32g .. 32g+31]
    float4 e[8];
    const float4* b2v = (const float4*)(b2 + 32 * g);
#pragma unroll
    for (int u = 0; u < 8; ++u) {
        float4 b = b2v[u];
        e[u].x = cnt * b.x; e[u].y = cnt * b.y;
        e[u].z = cnt * b.z; e[u].w = cnt * b.w;
    }

#pragma unroll
    for (int i = 0; i < 4; ++i) {
        const int kk = 4 * (g ^ i);
#pragma unroll
        for (int q = 0; q < 4; ++q) {
            const float sval = sg_[i][q];
            const float4* w2p = (const float4*)(W2 + (kk + q) * EMBED_DIM + 32 * g);
#pragma unroll
            for (int u = 0; u < 8; ++u) {   // 16 lanes (same g) share addrs -> L1/L2 dedup
                float4 w = w2p[u];
                e[u].x = fmaf(sval, w.x, e[u].x);
                e[u].y = fmaf(sval, w.y, e[u].y);
                e[u].z = fmaf(sval, w.z, e[u].z);
                e[u].w = fmaf(sval, w.w, e[u].w);
            }
        }
    }

    float4* op = (float4*)(out + (row0 + r) * EMBED_DIM + 32 * g);
#pragma unroll
    for (int u = 0; u < 8; ++u) {
        float4 o;
        o.x = e[u].x * inv; o.y = e[u].y * inv;
        o.z = e[u].z * inv; o.w = e[u].w * inv;
        op[u] = o;
    }
}

extern "C" void kernel_launch(void* const* d_in, const int* in_sizes, int n_in,
                              void* d_out, int out_size, void* d_ws, size_t ws_size,
                              hipStream_t stream) {
    const float* M  = (const float*)d_in[0];   // [50000, 2000]
    const float* W1 = (const float*)d_in[1];   // [1, 16]
    const float* b1 = (const float*)d_in[2];   // [16]
    const float* W2 = (const float*)d_in[3];   // [16, 128]
    const float* b2 = (const float*)d_in[4];   // [128]
    float* out = (float*)d_out;                // [50000, 128]

    fused_gather_mean_kernel<<<NUM_LEARNERS / 16, 64, 0, stream>>>(
        M, W1, b1, W2, b2, out);
}